// Round 4
// baseline (214.753 us; speedup 1.0000x reference)
//
#include <hip/hip_runtime.h>
#include <hip/hip_bf16.h>

// Causal flash attention fwd. B=2,H=16,S=2048,D=128, fp32 io, bf16 MFMA.
// R4: padded-stride LDS (K:272B, V:144B rows) -> conflict-free + immediate-offset
// ds_reads; v_cvt_pk_bf16_f32 packing; exp2 softmax; skip O-rescale when alpha==1.
constexpr int Bb = 2, Hh = 16, Ss = 2048, Dd = 128;
constexpr int BM = 64, BN = 64;
constexpr int NQT = Ss / BM;
// 1/sqrt(128) * log2(e): softmax computed in exp2 domain.
constexpr float SCALE = 0.088388347648318447f * 1.4426950408889634f;

constexpr int KSTRIDE = 272;   // bytes per K row (64 rows)  -> 17408 B
constexpr int VSTRIDE = 144;   // bytes per Vt row (128 rows) -> 18432 B

typedef __attribute__((ext_vector_type(8))) short bf16x8;
typedef __attribute__((ext_vector_type(4))) float f32x4;
typedef __attribute__((ext_vector_type(4))) int int4v;

__device__ __forceinline__ unsigned bfbits(float f) {
  union { float f; unsigned u; } v; v.f = f;
  return v.u + 0x7FFFu + ((v.u >> 16) & 1u);     // RNE; bf16 = bits[31:16]
}
__device__ __forceinline__ unsigned pkbf(float lo, float hi) {
#if __has_builtin(__builtin_amdgcn_cvt_pk_bf16_f32)
  typedef __attribute__((ext_vector_type(2))) __bf16 bf16x2;
  bf16x2 r = __builtin_amdgcn_cvt_pk_bf16_f32(lo, hi);
  return __builtin_bit_cast(unsigned, r);
#else
  return __builtin_amdgcn_perm(bfbits(hi), bfbits(lo), 0x07060302u);
#endif
}
__device__ __forceinline__ float exp2fast(float x) {
#if __has_builtin(__builtin_amdgcn_exp2f)
  return __builtin_amdgcn_exp2f(x);
#else
  return exp2f(x);
#endif
}
__device__ __forceinline__ float fcomp(float4 f, int j) {   // j unroll-constant
  return j == 0 ? f.x : (j == 1 ? f.y : (j == 2 ? f.z : f.w));
}

__global__ __launch_bounds__(256, 3)
void fa_fwd_kernel(const float* __restrict__ q, const float* __restrict__ k,
                   const float* __restrict__ v, float* __restrict__ out) {
  __shared__ __align__(16) char Klds[BN * KSTRIDE];    // K[key][d] bf16, padded rows
  __shared__ __align__(16) char Vlds[Dd * VSTRIDE];    // Vt[d][key] bf16, padded rows

  const int tid = threadIdx.x;
  const int wave = tid >> 6, lane = tid & 63, quad = lane >> 4, l16 = lane & 15;
  const int bid = blockIdx.x;
  const int bh = bid & 31;
  const int qt = (NQT - 1) - (bid >> 5);           // heavy tiles first

  const float* qb = q + (size_t)bh * Ss * Dd;
  const float* kb = k + (size_t)bh * Ss * Dd;
  const float* vb = v + (size_t)bh * Ss * Dd;

  // ---- Q fragments (scale*log2e folded). qrow = wave*16 + l16, d = 32ks+8quad+j
  bf16x8 qf[4];
  {
    const float* qr = qb + (size_t)(qt * BM + wave * 16 + l16) * Dd + quad * 8;
    #pragma unroll
    for (int ks = 0; ks < 4; ++ks) {
      float4 a = *(const float4*)(qr + ks * 32);
      float4 b = *(const float4*)(qr + ks * 32 + 4);
      int4v t = { (int)pkbf(a.x*SCALE, a.y*SCALE), (int)pkbf(a.z*SCALE, a.w*SCALE),
                  (int)pkbf(b.x*SCALE, b.y*SCALE), (int)pkbf(b.z*SCALE, b.w*SCALE) };
      qf[ks] = __builtin_bit_cast(bf16x8, t);
    }
  }

  // ---- staging geometry
  // K: thread owns rows krow0+16i (i<4), d-block kblk (8 d each); b128 writes.
  const int krow0 = tid >> 4;            // 0..15
  const int kblk  = tid & 15;            // d/8
  // V: thread owns keys vkg*8..+7, d = 4*vdq..+3; writes Vt rows d as b128.
  const int vdq = tid >> 3;              // 0..31
  const int vkg = tid & 7;               // 0..7

  float4 ka[4], kc[4];                   // K prefetch (8 fp32 per row)
  float4 vr[8];                          // V prefetch (8 key-rows x 4 d)

  auto load_tiles = [&](int kt) {
    const float* Kg = kb + (size_t)(kt * BN) * Dd + kblk * 8;
    #pragma unroll
    for (int i = 0; i < 4; ++i) {
      ka[i] = *(const float4*)(Kg + (size_t)(krow0 + 16 * i) * Dd);
      kc[i] = *(const float4*)(Kg + (size_t)(krow0 + 16 * i) * Dd + 4);
    }
    const float* Vg = vb + (size_t)(kt * BN + vkg * 8) * Dd + vdq * 4;
    #pragma unroll
    for (int r = 0; r < 8; ++r)
      vr[r] = *(const float4*)(Vg + (size_t)r * Dd);
  };

  auto stage_tiles = [&]() {
    #pragma unroll
    for (int i = 0; i < 4; ++i) {
      int4v t = { (int)pkbf(ka[i].x, ka[i].y), (int)pkbf(ka[i].z, ka[i].w),
                  (int)pkbf(kc[i].x, kc[i].y), (int)pkbf(kc[i].z, kc[i].w) };
      *(int4v*)(Klds + (krow0 + 16 * i) * KSTRIDE + kblk * 16) = t;
    }
    #pragma unroll
    for (int j = 0; j < 4; ++j) {
      int d = vdq * 4 + j;
      int4v t = { (int)pkbf(fcomp(vr[0], j), fcomp(vr[1], j)),
                  (int)pkbf(fcomp(vr[2], j), fcomp(vr[3], j)),
                  (int)pkbf(fcomp(vr[4], j), fcomp(vr[5], j)),
                  (int)pkbf(fcomp(vr[6], j), fcomp(vr[7], j)) };
      *(int4v*)(Vlds + d * VSTRIDE + vkg * 16) = t;
    }
  };

  f32x4 o[8];
  #pragma unroll
  for (int i = 0; i < 8; ++i) o[i] = (f32x4)(0.0f);
  float mrow = -3.0e38f, lrow = 0.0f;    // per-lane: qrow = wave*16 + l16

  load_tiles(0);
  stage_tiles();

  const int hi2 = quad >> 1;
  const int srcbase = (l16 + 32 * (quad & 1)) * 4;     // bpermute byte base
  // loop-invariant LDS read bases (all read offsets are immediates from these)
  const char* Krd = Klds + l16 * KSTRIDE + quad * 16;
  const char* Vrd = Vlds + l16 * VSTRIDE + quad * 16;

  for (int kt = 0; kt <= qt; ++kt) {
    __syncthreads();                     // tile kt visible
    const bool more = kt < qt;
    if (more) load_tiles(kt + 1);        // prefetch next tile, resolve at loop end

    // ---- S^T: acc[nt][r] = S[qrow=l16][key = nt*16 + quad*4 + r] (log2 units)
    f32x4 acc[4];
    #pragma unroll
    for (int nt = 0; nt < 4; ++nt) acc[nt] = (f32x4)(0.0f);
    #pragma unroll
    for (int ks = 0; ks < 4; ++ks) {
      #pragma unroll
      for (int nt = 0; nt < 4; ++nt) {
        bf16x8 kf = *(const bf16x8*)(Krd + nt * (16 * KSTRIDE) + ks * 64);
        acc[nt] = __builtin_amdgcn_mfma_f32_16x16x32_bf16(kf, qf[ks], acc[nt], 0, 0, 0);
      }
    }

    // ---- causal mask on diagonal tile
    if (kt == qt) {
      #pragma unroll
      for (int nt = 0; nt < 4; ++nt)
        #pragma unroll
        for (int r = 0; r < 4; ++r)
          if (nt * 16 + quad * 4 + r > wave * 16 + l16) acc[nt][r] = -1.0e30f;
    }

    // ---- online softmax (base-2); reduce across the 4 lanes sharing l16
    float mx = acc[0][0];
    #pragma unroll
    for (int nt = 0; nt < 4; ++nt)
      #pragma unroll
      for (int r = 0; r < 4; ++r) mx = fmaxf(mx, acc[nt][r]);
    mx = fmaxf(mx, __shfl_xor(mx, 16, 64));
    mx = fmaxf(mx, __shfl_xor(mx, 32, 64));
    float mn = fmaxf(mrow, mx);
    float alpha = 1.0f;
    if (__any(mx > mrow)) {              // some row's max updated -> rescale O
      alpha = exp2fast(mrow - mn);
      #pragma unroll
      for (int r = 0; r < 4; ++r) {
        int src = (lane & 48) | (quad * 4 + r);
        float ar = __shfl(alpha, src, 64);
        #pragma unroll
        for (int dt = 0; dt < 8; ++dt) o[dt][r] *= ar;
      }
    }
    mrow = mn;
    float rs = 0.f;
    #pragma unroll
    for (int nt = 0; nt < 4; ++nt)
      #pragma unroll
      for (int r = 0; r < 4; ++r) {
        float p = exp2fast(acc[nt][r] - mn);
        acc[nt][r] = p; rs += p;
      }
    rs += __shfl_xor(rs, 16, 64);
    rs += __shfl_xor(rs, 32, 64);
    lrow = lrow * alpha + rs;

    // ---- pack P (bf16 pairs), keys nt*16+quad*4+{0,1} / {2,3}
    unsigned pk0_0 = pkbf(acc[0][0], acc[0][1]), pk0_1 = pkbf(acc[0][2], acc[0][3]);
    unsigned pk1_0 = pkbf(acc[1][0], acc[1][1]), pk1_1 = pkbf(acc[1][2], acc[1][3]);
    unsigned pk2_0 = pkbf(acc[2][0], acc[2][1]), pk2_1 = pkbf(acc[2][2], acc[2][3]);
    unsigned pk3_0 = pkbf(acc[3][0], acc[3][1]), pk3_1 = pkbf(acc[3][2], acc[3][3]);

    // ---- P A-fragments via bpermute among the 4 lanes sharing l16
    bf16x8 pf[2];
    {
      int4v p0, p1;
      #pragma unroll
      for (int jp = 0; jp < 4; ++jp) {
        int srcb = srcbase + 64 * (jp >> 1);
        int a0 = __builtin_amdgcn_ds_bpermute(srcb, (int)((jp & 1) ? pk0_1 : pk0_0));
        int a1 = __builtin_amdgcn_ds_bpermute(srcb, (int)((jp & 1) ? pk1_1 : pk1_0));
        int a2 = __builtin_amdgcn_ds_bpermute(srcb, (int)((jp & 1) ? pk2_1 : pk2_0));
        int a3 = __builtin_amdgcn_ds_bpermute(srcb, (int)((jp & 1) ? pk3_1 : pk3_0));
        p0[jp] = hi2 ? a1 : a0;
        p1[jp] = hi2 ? a3 : a2;
      }
      pf[0] = __builtin_bit_cast(bf16x8, p0);
      pf[1] = __builtin_bit_cast(bf16x8, p1);
    }

    // ---- O += P V
    #pragma unroll
    for (int ks2 = 0; ks2 < 2; ++ks2) {
      #pragma unroll
      for (int dt = 0; dt < 8; ++dt) {
        bf16x8 vf = *(const bf16x8*)(Vrd + dt * (16 * VSTRIDE) + ks2 * 64);
        o[dt] = __builtin_amdgcn_mfma_f32_16x16x32_bf16(pf[ks2], vf, o[dt], 0, 0, 0);
      }
    }

    if (more) { __syncthreads(); stage_tiles(); }   // prefetch resolves here
  }

  // ---- epilogue: O / l
  float linv[4];
  #pragma unroll
  for (int r = 0; r < 4; ++r) {
    int src = (lane & 48) | (quad * 4 + r);
    linv[r] = 1.0f / __shfl(lrow, src, 64);
  }
  float* ob = out + ((size_t)bh * Ss + qt * BM + wave * 16) * Dd;
  #pragma unroll
  for (int dt = 0; dt < 8; ++dt)
    #pragma unroll
    for (int r = 0; r < 4; ++r)
      ob[(quad * 4 + r) * Dd + dt * 16 + l16] = o[dt][r] * linv[r];
}

extern "C" void kernel_launch(void* const* d_in, const int* in_sizes, int n_in,
                              void* d_out, int out_size, void* d_ws, size_t ws_size,
                              hipStream_t stream) {
  const float* q = (const float*)d_in[0];
  const float* k = (const float*)d_in[1];
  const float* v = (const float*)d_in[2];
  float* out = (float*)d_out;
  dim3 grid(Bb * Hh * NQT);   // 1024
  dim3 block(256);
  hipLaunchKernelGGL(fa_fwd_kernel, grid, block, 0, stream, q, k, v, out);
}